// Round 5
// baseline (130.775 us; speedup 1.0000x reference)
//
#include <hip/hip_runtime.h>
#include <hip/hip_bf16.h>

// B=8, T1=128, T2=256, C=256, H=8, hd=32, E=32, A1=16, NTYPE=3. fp32 in HBM.
// Round 13: 2-kernel pipeline. proj2 deleted -> attention blocks atomicAdd
// their K=32 proj partials straight into out (harness zeroes out first);
// aux term handled by 16 extra blocks in the same kernel (recompute Weff in
// LDS from prep's WpT + raw Wv -> no intra-kernel dependency). x1b/A2
// staging deleted: attention loads raw fp32 x1/x2/ax2 + cvt8 (bit-identical
// bf16 frags, more outstanding loads). prep = 604 blocks (masks, W
// transposes, ax1p). Attention grid back to r11's verified 192-block shape.
#define NC 256
#define HD 32

typedef __attribute__((ext_vector_type(8))) short short8;
typedef __attribute__((ext_vector_type(4))) short short4v;
typedef __attribute__((ext_vector_type(4))) float f32x4;

#define QSC (0.17677669529663687f * 1.4426950408889634f)  // 1/sqrt(32)*log2(e)

__device__ __forceinline__ unsigned short f2bf(float f) {
    union { float f; unsigned u; } v; v.f = f;
    unsigned r = v.u + 0x7fffu + ((v.u >> 16) & 1u);   // RNE
    return (unsigned short)(r >> 16);
}
__device__ __forceinline__ short8 cvt8(float4 a, float4 b) {
    short8 s;
    s[0] = (short)f2bf(a.x); s[1] = (short)f2bf(a.y);
    s[2] = (short)f2bf(a.z); s[3] = (short)f2bf(a.w);
    s[4] = (short)f2bf(b.x); s[5] = (short)f2bf(b.y);
    s[6] = (short)f2bf(b.z); s[7] = (short)f2bf(b.w);
    return s;
}

// ---------------------------------------------------------------------------
// prep: 604 blocks. masks (192) | WqT (96) | WkT/WvT (216) | WpT (96) | ax1p (4)
// ---------------------------------------------------------------------------
__global__ __launch_bounds__(256) void prep(
    const int* __restrict__ masks,
    const float* __restrict__ Wq, const float* __restrict__ Wk,
    const float* __restrict__ Wv, const float* __restrict__ Wp,
    const float* __restrict__ ax1,
    unsigned int* __restrict__ mb,
    short* __restrict__ WqT, short* __restrict__ WkT, short* __restrict__ WvT,
    short* __restrict__ WpT, short* __restrict__ ax1p)
{
    const int bx = blockIdx.x, tid = threadIdx.x;
    const short8 zero8 = {0, 0, 0, 0, 0, 0, 0, 0};

    if (bx < 192) {
        const int r0 = bx * 16;
        const int wave = tid >> 6, lane = tid & 63;
        for (int rr = 0; rr < 16; ++rr) {
            const int row = r0 + rr;
            const int mk = masks[(size_t)row * 256 + tid];
            unsigned long long bal = __ballot(mk != 0);
            if (lane == 0) {
                mb[row * 8 + wave * 2 + 0] = (unsigned int)bal;
                mb[row * 8 + wave * 2 + 1] = (unsigned int)(bal >> 32);
            }
        }
    } else if (bx < 288) {
        const int idx = bx - 192, i = idx >> 5, k8 = idx & 31;
        const int n = tid;
        const float* W = Wq + (size_t)i * 256 * 256;
        short8 s;
#pragma unroll
        for (int j = 0; j < 8; ++j) s[j] = (short)f2bf(W[(size_t)(k8 * 8 + j) * 256 + n]);
        *(short8*)&WqT[(size_t)i * 256 * 256 + (size_t)n * 256 + k8 * 8] = s;
    } else if (bx < 504) {
        const int idx0 = bx - 288;
        const int kv = idx0 / 108, idx = idx0 % 108;
        const int i = idx / 36, k8 = idx % 36;
        const int n = tid;
        const float* W = (kv ? Wv : Wk) + (size_t)i * 288 * 256;
        short* O = (kv ? WvT : WkT) + (size_t)i * 256 * 288;
        short8 s;
#pragma unroll
        for (int j = 0; j < 8; ++j) {
            const int kp = k8 * 8 + j;
            const int src = (kp < 256) ? kp : (kp < 272 ? kp + 16 : -1);
            s[j] = (src >= 0) ? (short)f2bf(W[(size_t)src * 256 + n]) : (short)0;
        }
        *(short8*)&O[(size_t)n * 288 + k8 * 8] = s;
    } else if (bx < 600) {
        const int idx = bx - 504, i = idx >> 5, k8 = idx & 31;
        const int n = tid;
        const float* W = Wp + (size_t)i * 256 * 256;
        short8 s;
#pragma unroll
        for (int j = 0; j < 8; ++j) s[j] = (short)f2bf(W[(size_t)(k8 * 8 + j) * 256 + n]);
        *(short8*)&WpT[(size_t)i * 256 * 256 + (size_t)n * 256 + k8 * 8] = s;
    } else {
        const int row = (bx - 600) * 256 + tid;
        const float* p = ax1 + (size_t)row * 16;
        float4 a = *(const float4*)p,       b = *(const float4*)(p + 4);
        float4 c = *(const float4*)(p + 8), d = *(const float4*)(p + 12);
        short* o = ax1p + (size_t)row * 32;
        *(short8*)o        = cvt8(a, b);
        *(short8*)(o + 8)  = cvt8(c, d);
        *(short8*)(o + 16) = zero8;
        *(short8*)(o + 24) = zero8;
    }
}

// ---------------------------------------------------------------------------
// attn_proj: 208 blocks. bx<192: (i,b,h) full attention + proj partial
// atomicAdd. bx>=192: 16 aux blocks -> Weff in LDS + ax1@Weff + bias.
// ---------------------------------------------------------------------------
__global__ __launch_bounds__(256) void attn_proj(
    const float* __restrict__ x1, const float* __restrict__ x2,
    const float* __restrict__ ax2,
    const short* __restrict__ WqT, const short* __restrict__ WkT,
    const short* __restrict__ WvT, const float* __restrict__ Wv,
    const short* __restrict__ WpT,
    const float* __restrict__ bq, const float* __restrict__ bk,
    const float* __restrict__ bv, const short* __restrict__ ax1p,
    const unsigned int* __restrict__ mb, const float* __restrict__ bp,
    float* __restrict__ out)
{
    const int tid = threadIdx.x;
    const int wave = tid >> 6, lane = tid & 63;
    const int qd = lane >> 4, ml = lane & 15;
    const int bx = blockIdx.x;
    const short8 zero8 = {0, 0, 0, 0, 0, 0, 0, 0};

    __shared__ short q_s[128][40];     // 10240 B
    __shared__ short k_s[256][40];     // 20480 B
    __shared__ short vT_s[32][264];    // 16896 B
    __shared__ short P_s[4][2048];     // 16384 B (aux blocks reuse as Weff)
    __shared__ short O_s[4][32][40];   // 10240 B  -> 74240 total

    if (bx >= 192) {   // ---- aux blocks: Weff + ax1@Weff + bias ----
        const int ab = bx - 192;       // 0..15
        short* Wl = &P_s[0][0];        // Weff_lds flat [n][32], 8192 shorts
        f32x4 wacc[4];
#pragma unroll
        for (int nt = 0; nt < 4; ++nt) wacc[nt] = {0.f, 0.f, 0.f, 0.f};
        for (int i = 0; i < 3; ++i) {
            const float* Wvp = Wv + (size_t)i * 288 * 256;
            const short* Wpt = WpT + (size_t)i * 256 * 256;
            for (int step = 0; step < 8; ++step) {
                const float* ap = Wvp + (size_t)(256 + ml) * 256 + step * 32 + qd * 8;
                short8 af = cvt8(*(const float4*)ap, *(const float4*)(ap + 4));
#pragma unroll
                for (int nt = 0; nt < 4; ++nt) {
                    const int n = (wave * 4 + nt) * 16 + ml;
                    short8 bf = *(const short8*)&Wpt[(size_t)n * 256 + step * 32 + qd * 8];
                    wacc[nt] = __builtin_amdgcn_mfma_f32_16x16x32_bf16(af, bf, wacc[nt], 0, 0, 0);
                }
            }
        }
#pragma unroll
        for (int nt = 0; nt < 4; ++nt) {
            const int n = (wave * 4 + nt) * 16 + ml;
#pragma unroll
            for (int r = 0; r < 4; ++r) {
                Wl[n * 32 + qd * 4 + r] = (short)f2bf(wacc[nt][r]);
                Wl[n * 32 + 16 + qd * 4 + r] = 0;
            }
        }
        __syncthreads();
        const int m0 = ab * 64 + wave * 16;
        short8 af = *(const short8*)&ax1p[(size_t)(m0 + ml) * 32 + qd * 8];
        const int row0 = m0 + qd * 4;
#pragma unroll
        for (int nt = 0; nt < 16; ++nt) {
            const int col = nt * 16 + ml;
            short8 bf = *(const short8*)&Wl[col * 32 + qd * 8];
            f32x4 z = {0.f, 0.f, 0.f, 0.f};
            f32x4 acc = __builtin_amdgcn_mfma_f32_16x16x32_bf16(af, bf, z, 0, 0, 0);
            const float b3 = bp[col] + bp[256 + col] + bp[512 + col];
#pragma unroll
            for (int r = 0; r < 4; ++r)
                atomicAdd(&out[(size_t)(row0 + r) * 256 + col], acc[r] + b3);
        }
        return;
    }

    const int i = bx >> 6, b = (bx >> 3) & 7, h = bx & 7;
    const size_t bb = (size_t)i * 8 + b;
    const int hc = h * 32;

    const short* Wq_i = WqT + (size_t)i * 256 * 256;
    const short* Wk_i = WkT + (size_t)i * 256 * 288;
    const short* Wv_i = WvT + (size_t)i * 256 * 288;

    // ---- fused Q+K+V GEMMs: raw fp32 activations + cvt8, staged weights ----
    f32x4 qacc[2][2], kacc[4][2], vacc[4][2];
#pragma unroll
    for (int mt = 0; mt < 2; ++mt)
#pragma unroll
        for (int nt = 0; nt < 2; ++nt) qacc[mt][nt] = {0.f, 0.f, 0.f, 0.f};
#pragma unroll
    for (int mt = 0; mt < 4; ++mt)
#pragma unroll
        for (int nt = 0; nt < 2; ++nt) {
            kacc[mt][nt] = {0.f, 0.f, 0.f, 0.f};
            vacc[mt][nt] = {0.f, 0.f, 0.f, 0.f};
        }

    for (int step = 0; step < 8; ++step) {
        short8 afq[2], bfq[2], af[4], bfk[2], bfv[2];
#pragma unroll
        for (int mt = 0; mt < 2; ++mt) {
            const float* px = x1 + (size_t)(b * 128 + wave * 32 + mt * 16 + ml) * 256 + step * 32 + qd * 8;
            afq[mt] = cvt8(*(const float4*)px, *(const float4*)(px + 4));
        }
#pragma unroll
        for (int nt = 0; nt < 2; ++nt)
            bfq[nt] = *(const short8*)&Wq_i[(size_t)(hc + nt * 16 + ml) * 256 + step * 32 + qd * 8];
#pragma unroll
        for (int mt = 0; mt < 4; ++mt) {
            const float* pa = x2 + (size_t)(b * 256 + wave * 64 + mt * 16 + ml) * 256 + step * 32 + qd * 8;
            af[mt] = cvt8(*(const float4*)pa, *(const float4*)(pa + 4));
        }
#pragma unroll
        for (int nt = 0; nt < 2; ++nt) {
            bfk[nt] = *(const short8*)&Wk_i[(size_t)(hc + nt * 16 + ml) * 288 + step * 32 + qd * 8];
            bfv[nt] = *(const short8*)&Wv_i[(size_t)(hc + nt * 16 + ml) * 288 + step * 32 + qd * 8];
        }
#pragma unroll
        for (int mt = 0; mt < 2; ++mt)
#pragma unroll
            for (int nt = 0; nt < 2; ++nt)
                qacc[mt][nt] = __builtin_amdgcn_mfma_f32_16x16x32_bf16(afq[mt], bfq[nt], qacc[mt][nt], 0, 0, 0);
#pragma unroll
        for (int mt = 0; mt < 4; ++mt)
#pragma unroll
            for (int nt = 0; nt < 2; ++nt) {
                kacc[mt][nt] = __builtin_amdgcn_mfma_f32_16x16x32_bf16(af[mt], bfk[nt], kacc[mt][nt], 0, 0, 0);
                vacc[mt][nt] = __builtin_amdgcn_mfma_f32_16x16x32_bf16(af[mt], bfv[nt], vacc[mt][nt], 0, 0, 0);
            }
    }
    {   // peeled step 8: K/V only; A2 cols 256..287 = [ax2 | zeros]
        const int step = 8;
        short8 af[4], bfk[2], bfv[2];
#pragma unroll
        for (int mt = 0; mt < 4; ++mt) {
            if (qd < 2) {
                const float* pa = ax2 + (size_t)(b * 256 + wave * 64 + mt * 16 + ml) * 16 + qd * 8;
                af[mt] = cvt8(*(const float4*)pa, *(const float4*)(pa + 4));
            } else {
                af[mt] = zero8;
            }
        }
#pragma unroll
        for (int nt = 0; nt < 2; ++nt) {
            bfk[nt] = *(const short8*)&Wk_i[(size_t)(hc + nt * 16 + ml) * 288 + step * 32 + qd * 8];
            bfv[nt] = *(const short8*)&Wv_i[(size_t)(hc + nt * 16 + ml) * 288 + step * 32 + qd * 8];
        }
#pragma unroll
        for (int mt = 0; mt < 4; ++mt)
#pragma unroll
            for (int nt = 0; nt < 2; ++nt) {
                kacc[mt][nt] = __builtin_amdgcn_mfma_f32_16x16x32_bf16(af[mt], bfk[nt], kacc[mt][nt], 0, 0, 0);
                vacc[mt][nt] = __builtin_amdgcn_mfma_f32_16x16x32_bf16(af[mt], bfv[nt], vacc[mt][nt], 0, 0, 0);
            }
    }

    // ---- epilogues to LDS ----
#pragma unroll
    for (int nt = 0; nt < 2; ++nt) {
        const float bsq = bq[i * 256 + hc + nt * 16 + ml];
#pragma unroll
        for (int mt = 0; mt < 2; ++mt) {
            const int r0 = wave * 32 + mt * 16 + qd * 4;
#pragma unroll
            for (int r = 0; r < 4; ++r)
                q_s[r0 + r][nt * 16 + ml] = (short)f2bf((qacc[mt][nt][r] + bsq) * QSC);
        }
    }
#pragma unroll
    for (int nt = 0; nt < 2; ++nt) {
        const float bsk = bk[i * 256 + hc + nt * 16 + ml];
        const float bsvv = bv[i * 256 + hc + nt * 16 + ml];
#pragma unroll
        for (int mt = 0; mt < 4; ++mt) {
            const int s0 = wave * 64 + mt * 16 + qd * 4;
#pragma unroll
            for (int r = 0; r < 4; ++r)
                k_s[s0 + r][nt * 16 + ml] = (short)f2bf(kacc[mt][nt][r] + bsk);
            short4v s;
            s.x = (short)f2bf(vacc[mt][nt][0] + bsvv);
            s.y = (short)f2bf(vacc[mt][nt][1] + bsvv);
            s.z = (short)f2bf(vacc[mt][nt][2] + bsvv);
            s.w = (short)f2bf(vacc[mt][nt][3] + bsvv);
            *(short4v*)&vT_s[nt * 16 + ml][s0] = s;
        }
    }
    __syncthreads();

    // ---- attention; wave owns t rows wave*32..+32; O into O_s ----
    short* Pw = &P_s[wave][0];
    for (int mt = 0; mt < 2; ++mt) {
        const int t0 = wave * 32 + mt * 16;
        const int tb = t0 + qd * 4;

        uint4 wlo[4], whi[4];
#pragma unroll
        for (int r = 0; r < 4; ++r) {
            const unsigned int* p = mb + (bb * 128 + tb + r) * 8;
            wlo[r] = *(const uint4*)p;
            whi[r] = *(const uint4*)(p + 4);
        }

        short8 af = *(const short8*)&q_s[t0 + ml][qd * 8];

        f32x4 sacc[16];
#pragma unroll
        for (int nt = 0; nt < 16; ++nt) sacc[nt] = {0.f, 0.f, 0.f, 0.f};
#pragma unroll
        for (int nt = 0; nt < 16; ++nt) {
            short8 bf = *(const short8*)&k_s[nt * 16 + ml][qd * 8];
            sacc[nt] = __builtin_amdgcn_mfma_f32_16x16x32_bf16(af, bf, sacc[nt], 0, 0, 0);
        }

        f32x4 rs = {0.f, 0.f, 0.f, 0.f};
#pragma unroll
        for (int nt = 0; nt < 16; ++nt) {
#pragma unroll
            for (int r = 0; r < 4; ++r) {
                unsigned int w;
                switch (nt >> 1) {
                    case 0: w = wlo[r].x; break; case 1: w = wlo[r].y; break;
                    case 2: w = wlo[r].z; break; case 3: w = wlo[r].w; break;
                    case 4: w = whi[r].x; break; case 5: w = whi[r].y; break;
                    case 6: w = whi[r].z; break; default: w = whi[r].w; break;
                }
                const bool mk = (w >> ((nt & 1) * 16 + ml)) & 1u;
                float e = mk ? __builtin_amdgcn_exp2f(sacc[nt][r]) : 0.f;
                sacc[nt][r] = e;
                rs[r] += e;
            }
        }
#pragma unroll
        for (int off = 1; off <= 8; off <<= 1) {
#pragma unroll
            for (int r = 0; r < 4; ++r) rs[r] += __shfl_xor(rs[r], off);
        }
        f32x4 pinv, pfill;
#pragma unroll
        for (int r = 0; r < 4; ++r) {
            const bool z = (rs[r] == 0.f);
            pinv[r]  = z ? 0.f : 1.f / rs[r];
            pfill[r] = z ? (1.f / 256.f) : 0.f;
        }

        f32x4 oacc[2];
        oacc[0] = {0.f, 0.f, 0.f, 0.f};
        oacc[1] = {0.f, 0.f, 0.f, 0.f};
#pragma unroll
        for (int half = 0; half < 2; ++half) {
#pragma unroll
            for (int nt8 = 0; nt8 < 8; ++nt8) {
                const int nt = half * 8 + nt8;
                const int sgrp = 2 * nt8 + (ml >> 3);
                const int pos = ml & 7;
#pragma unroll
                for (int r = 0; r < 4; ++r) {
                    const float p = sacc[nt][r] * pinv[r] + pfill[r];
                    Pw[(sgrp * 16 + qd * 4 + r) * 8 + pos] = (short)f2bf(p);
                }
            }
#pragma unroll
            for (int ksl = 0; ksl < 4; ++ksl) {
                const int ks = half * 4 + ksl;
                short8 pa = *(const short8*)&Pw[((ksl * 4 + qd) * 16 + ml) * 8];
#pragma unroll
                for (int n2 = 0; n2 < 2; ++n2) {
                    short8 vf = *(const short8*)&vT_s[n2 * 16 + ml][ks * 32 + qd * 8];
                    oacc[n2] = __builtin_amdgcn_mfma_f32_16x16x32_bf16(pa, vf, oacc[n2], 0, 0, 0);
                }
            }
        }

#pragma unroll
        for (int n2 = 0; n2 < 2; ++n2)
#pragma unroll
            for (int r = 0; r < 4; ++r)
                O_s[wave][mt * 16 + qd * 4 + r][n2 * 16 + ml] = (short)f2bf(oacc[n2][r]);
    }

    // ---- proj partial: (O @ Wp_i[hc:hc+32, :]) -> atomicAdd into out ----
    const short* Wp_i = WpT + (size_t)i * 256 * 256;
    short8 afA = *(const short8*)&O_s[wave][ml][qd * 8];
    short8 afB = *(const short8*)&O_s[wave][16 + ml][qd * 8];
    const int trow0 = b * 128 + wave * 32 + qd * 4;
#pragma unroll
    for (int nt = 0; nt < 16; ++nt) {
        const int col = nt * 16 + ml;
        short8 bf = *(const short8*)&Wp_i[(size_t)col * 256 + hc + qd * 8];
        f32x4 z = {0.f, 0.f, 0.f, 0.f};
        f32x4 p0 = __builtin_amdgcn_mfma_f32_16x16x32_bf16(afA, bf, z, 0, 0, 0);
        f32x4 p1 = __builtin_amdgcn_mfma_f32_16x16x32_bf16(afB, bf, z, 0, 0, 0);
#pragma unroll
        for (int r = 0; r < 4; ++r) {
            atomicAdd(&out[(size_t)(trow0 + r) * 256 + col], p0[r]);
            atomicAdd(&out[(size_t)(trow0 + 16 + r) * 256 + col], p1[r]);
        }
    }
}

extern "C" void kernel_launch(void* const* d_in, const int* in_sizes, int n_in,
                              void* d_out, int out_size, void* d_ws, size_t ws_size,
                              hipStream_t stream)
{
    const float* x1  = (const float*)d_in[0];
    const float* x2  = (const float*)d_in[1];
    const float* ax1 = (const float*)d_in[2];
    const float* ax2 = (const float*)d_in[3];
    const int*   mk  = (const int*)d_in[4];
    const float* Wq  = (const float*)d_in[5];
    const float* bq  = (const float*)d_in[6];
    const float* Wk  = (const float*)d_in[7];
    const float* bk  = (const float*)d_in[8];
    const float* Wv  = (const float*)d_in[9];
    const float* bv  = (const float*)d_in[10];
    const float* Wp  = (const float*)d_in[11];
    const float* bp  = (const float*)d_in[12];

    char* w = (char*)d_ws;
    short* ax1p  = (short*)(w + 1703936);        // 64 KB
    short* WqT   = (short*)(w + 1769472);        // 384 KB
    short* WkT   = (short*)(w + 2162688);        // 432 KB
    short* WvT   = (short*)(w + 2605056);        // 432 KB
    short* WpT   = (short*)(w + 3047424);        // 384 KB
    unsigned int* mbits = (unsigned int*)(w + 3440640);   // 96 KB

    prep<<<dim3(604), 256, 0, stream>>>(mk, Wq, Wk, Wv, Wp, ax1,
                                        mbits, WqT, WkT, WvT, WpT, ax1p);
    attn_proj<<<dim3(208), 256, 0, stream>>>(x1, x2, ax2,
                                             WqT, WkT, WvT, Wv, WpT,
                                             bq, bk, bv, ax1p, mbits, bp,
                                             (float*)d_out);
}

// Round 6
// 116.211 us; speedup vs baseline: 1.1253x; 1.1253x over previous
//
#include <hip/hip_runtime.h>
#include <hip/hip_bf16.h>

// B=8, T1=128, T2=256, C=256, H=8, hd=32, E=32, A1=16, NTYPE=3. fp32 in HBM.
// Round 14: revert to r11 3-kernel structure (best verified, 115.9us);
// qkv_attn re-partitioned to 16 waves/block (1024 threads), SAME total work:
// K/V s-rows spread 1 x 16-row chunk per wave (was 4 chunks on 4 waves),
// Q/attn on waves 0-7 (16 t-rows each). P scratch quartered (group offset
// applied to both write sgrp and read slot; ks order 0..7 preserved) ->
// LDS still 64000B. All fragments/MFMA K-orders unchanged -> bit-identical.
// Fixes r11's 0.75 waves/SIMD latency exposure (43.8us @ 2.3% MfmaUtil).
// prep/proj2 byte-identical to r11.
#define NC 256
#define HD 32

typedef __attribute__((ext_vector_type(8))) short short8;
typedef __attribute__((ext_vector_type(4))) short short4v;
typedef __attribute__((ext_vector_type(4))) float f32x4;

#define QSC (0.17677669529663687f * 1.4426950408889634f)  // 1/sqrt(32)*log2(e)

__device__ __forceinline__ unsigned short f2bf(float f) {
    union { float f; unsigned u; } v; v.f = f;
    unsigned r = v.u + 0x7fffu + ((v.u >> 16) & 1u);   // RNE
    return (unsigned short)(r >> 16);
}
__device__ __forceinline__ short8 cvt8(float4 a, float4 b) {
    short8 s;
    s[0] = (short)f2bf(a.x); s[1] = (short)f2bf(a.y);
    s[2] = (short)f2bf(a.z); s[3] = (short)f2bf(a.w);
    s[4] = (short)f2bf(b.x); s[5] = (short)f2bf(b.y);
    s[6] = (short)f2bf(b.z); s[7] = (short)f2bf(b.w);
    return s;
}

// ---------------------------------------------------------------------------
// prep (UNCHANGED from r11): activations + masks + weight transposes.
// ---------------------------------------------------------------------------
__global__ __launch_bounds__(256) void prep(
    const float* __restrict__ x1, const float* __restrict__ x2,
    const float* __restrict__ ax1, const float* __restrict__ ax2,
    const int* __restrict__ masks,
    const float* __restrict__ Wq, const float* __restrict__ Wk,
    const float* __restrict__ Wv, const float* __restrict__ Wp,
    short* __restrict__ x1b, short* __restrict__ A2, short* __restrict__ ax1p,
    unsigned int* __restrict__ mb,
    short* __restrict__ WqT, short* __restrict__ WkT, short* __restrict__ WvT,
    short* __restrict__ WpT)
{
    const int bx = blockIdx.x, tid = threadIdx.x;
    const short8 zero8 = {0, 0, 0, 0, 0, 0, 0, 0};

    if (bx < 64) {
        const size_t base = ((size_t)bx * 256 + tid) * 16;
        const float* p = x1 + base;
        float4 a = *(const float4*)p,       b = *(const float4*)(p + 4);
        float4 c = *(const float4*)(p + 8), d = *(const float4*)(p + 12);
        *(short8*)&x1b[base]     = cvt8(a, b);
        *(short8*)&x1b[base + 8] = cvt8(c, d);
    } else if (bx < 352) {
        const int g = (bx - 64) * 256 + tid;
        const int row = g / 36, c8 = g - row * 36;
        short8 s;
        if (c8 < 32) {
            const float* p = x2 + (size_t)row * 256 + c8 * 8;
            s = cvt8(*(const float4*)p, *(const float4*)(p + 4));
        } else if (c8 < 34) {
            const float* p = ax2 + (size_t)row * 16 + (c8 - 32) * 8;
            s = cvt8(*(const float4*)p, *(const float4*)(p + 4));
        } else {
            s = zero8;
        }
        *(short8*)&A2[(size_t)row * 288 + c8 * 8] = s;
    } else if (bx < 356) {
        const int row = (bx - 352) * 256 + tid;
        const float* p = ax1 + (size_t)row * 16;
        float4 a = *(const float4*)p,       b = *(const float4*)(p + 4);
        float4 c = *(const float4*)(p + 8), d = *(const float4*)(p + 12);
        short* o = ax1p + (size_t)row * 32;
        *(short8*)o        = cvt8(a, b);
        *(short8*)(o + 8)  = cvt8(c, d);
        *(short8*)(o + 16) = zero8;
        *(short8*)(o + 24) = zero8;
    } else if (bx < 548) {
        const int r0 = (bx - 356) * 16;
        const int wave = tid >> 6, lane = tid & 63;
        for (int rr = 0; rr < 16; ++rr) {
            const int row = r0 + rr;
            const int mk = masks[(size_t)row * 256 + tid];
            unsigned long long bal = __ballot(mk != 0);
            if (lane == 0) {
                mb[row * 8 + wave * 2 + 0] = (unsigned int)bal;
                mb[row * 8 + wave * 2 + 1] = (unsigned int)(bal >> 32);
            }
        }
    } else if (bx < 644) {
        const int idx = bx - 548, i = idx >> 5, k8 = idx & 31;
        const int n = tid;
        const float* W = Wq + (size_t)i * 256 * 256;
        short8 s;
#pragma unroll
        for (int j = 0; j < 8; ++j) s[j] = (short)f2bf(W[(size_t)(k8 * 8 + j) * 256 + n]);
        *(short8*)&WqT[(size_t)i * 256 * 256 + (size_t)n * 256 + k8 * 8] = s;
    } else if (bx < 860) {
        const int idx0 = bx - 644;
        const int kv = idx0 / 108, idx = idx0 % 108;
        const int i = idx / 36, k8 = idx % 36;
        const int n = tid;
        const float* W = (kv ? Wv : Wk) + (size_t)i * 288 * 256;
        short* O = (kv ? WvT : WkT) + (size_t)i * 256 * 288;
        short8 s;
#pragma unroll
        for (int j = 0; j < 8; ++j) {
            const int kp = k8 * 8 + j;
            const int src = (kp < 256) ? kp : (kp < 272 ? kp + 16 : -1);
            s[j] = (src >= 0) ? (short)f2bf(W[(size_t)src * 256 + n]) : (short)0;
        }
        *(short8*)&O[(size_t)n * 288 + k8 * 8] = s;
    } else {
        const int idx = bx - 860, i = idx >> 5, k8 = idx & 31;
        const int n = tid;
        const float* W = Wp + (size_t)i * 256 * 256;
        short8 s;
#pragma unroll
        for (int j = 0; j < 8; ++j) s[j] = (short)f2bf(W[(size_t)(k8 * 8 + j) * 256 + n]);
        *(short8*)&WpT[(size_t)i * 256 * 256 + (size_t)n * 256 + k8 * 8] = s;
    }
}

// ---------------------------------------------------------------------------
// qkv_attn: 193 blocks x 1024 threads (16 waves). K/V: wave w owns s-rows
// [16w,16w+16). Q + attention: waves 0-7 own 16 t-rows each. Same fragments,
// same MFMA K-order as r11 -> bit-identical.
// ---------------------------------------------------------------------------
__global__ __launch_bounds__(1024) void qkv_attn(
    const short* __restrict__ x1b, const short* __restrict__ A2,
    const short* __restrict__ WqT, const short* __restrict__ WkT,
    const short* __restrict__ WvT, const float* __restrict__ Wv,
    const short* __restrict__ WpT,
    const float* __restrict__ bq, const float* __restrict__ bk,
    const float* __restrict__ bv, const unsigned int* __restrict__ mb,
    short* __restrict__ yb, short* __restrict__ WeffT)
{
    const int tid = threadIdx.x;
    const int wave = tid >> 6, lane = tid & 63;
    const int qd = lane >> 4, ml = lane & 15;
    const int bx = blockIdx.x;

    if (bx == 192) {   // WeffT = (sum_i Wv_a1_i @ Wp_i)^T  (waves 0..3 only)
        if (wave >= 4) return;
        f32x4 wacc[4];
#pragma unroll
        for (int nt = 0; nt < 4; ++nt) wacc[nt] = {0.f, 0.f, 0.f, 0.f};
        for (int i = 0; i < 3; ++i) {
            const float* Wvp = Wv + (size_t)i * 288 * 256;
            const short* Wpt = WpT + (size_t)i * 256 * 256;
            for (int step = 0; step < 8; ++step) {
                const float* ap = Wvp + (size_t)(256 + ml) * 256 + step * 32 + qd * 8;
                short8 af = cvt8(*(const float4*)ap, *(const float4*)(ap + 4));
#pragma unroll
                for (int nt = 0; nt < 4; ++nt) {
                    const int n = (wave * 4 + nt) * 16 + ml;
                    short8 bf = *(const short8*)&Wpt[(size_t)n * 256 + step * 32 + qd * 8];
                    wacc[nt] = __builtin_amdgcn_mfma_f32_16x16x32_bf16(af, bf, wacc[nt], 0, 0, 0);
                }
            }
        }
#pragma unroll
        for (int nt = 0; nt < 4; ++nt) {
            const int n = (wave * 4 + nt) * 16 + ml;
#pragma unroll
            for (int r = 0; r < 4; ++r) {
                WeffT[n * 32 + qd * 4 + r] = (short)f2bf(wacc[nt][r]);
                WeffT[n * 32 + 16 + qd * 4 + r] = 0;
            }
        }
        return;
    }

    const int i = bx >> 6, b = (bx >> 3) & 7, h = bx & 7;
    const size_t bb = (size_t)i * 8 + b;
    const int hc = h * 32;

    __shared__ short q_s[128][40];     // 10240 B
    __shared__ short k_s[256][40];     // 20480 B
    __shared__ short vT_s[32][264];    // 16896 B
    __shared__ short P_s[8][1024];     // 16384 B (4 s-quarters per wave)

    const short* Wq_i = WqT + (size_t)i * 256 * 256;
    const short* Wk_i = WkT + (size_t)i * 256 * 288;
    const short* Wv_i = WvT + (size_t)i * 256 * 288;

    // ---- fused Q+K+V GEMMs: wave w owns K/V s-rows [16w,+16); Q on w<8 ----
    f32x4 qacc[2], kacc[2], vacc[2];
#pragma unroll
    for (int nt = 0; nt < 2; ++nt) {
        qacc[nt] = {0.f, 0.f, 0.f, 0.f};
        kacc[nt] = {0.f, 0.f, 0.f, 0.f};
        vacc[nt] = {0.f, 0.f, 0.f, 0.f};
    }

    for (int step = 0; step < 8; ++step) {
        short8 afq, bfq[2], af, bfk[2], bfv[2];
        if (wave < 8) {
            afq = *(const short8*)&x1b[(size_t)(b * 128 + wave * 16 + ml) * 256 + step * 32 + qd * 8];
#pragma unroll
            for (int nt = 0; nt < 2; ++nt)
                bfq[nt] = *(const short8*)&Wq_i[(size_t)(hc + nt * 16 + ml) * 256 + step * 32 + qd * 8];
        }
        af = *(const short8*)&A2[(size_t)(b * 256 + wave * 16 + ml) * 288 + step * 32 + qd * 8];
#pragma unroll
        for (int nt = 0; nt < 2; ++nt) {
            bfk[nt] = *(const short8*)&Wk_i[(size_t)(hc + nt * 16 + ml) * 288 + step * 32 + qd * 8];
            bfv[nt] = *(const short8*)&Wv_i[(size_t)(hc + nt * 16 + ml) * 288 + step * 32 + qd * 8];
        }
        if (wave < 8) {
#pragma unroll
            for (int nt = 0; nt < 2; ++nt)
                qacc[nt] = __builtin_amdgcn_mfma_f32_16x16x32_bf16(afq, bfq[nt], qacc[nt], 0, 0, 0);
        }
#pragma unroll
        for (int nt = 0; nt < 2; ++nt) {
            kacc[nt] = __builtin_amdgcn_mfma_f32_16x16x32_bf16(af, bfk[nt], kacc[nt], 0, 0, 0);
            vacc[nt] = __builtin_amdgcn_mfma_f32_16x16x32_bf16(af, bfv[nt], vacc[nt], 0, 0, 0);
        }
    }
    {   // peeled step 8: K/V only (A2/W cols 256..287)
        const int step = 8;
        short8 af, bfk[2], bfv[2];
        af = *(const short8*)&A2[(size_t)(b * 256 + wave * 16 + ml) * 288 + step * 32 + qd * 8];
#pragma unroll
        for (int nt = 0; nt < 2; ++nt) {
            bfk[nt] = *(const short8*)&Wk_i[(size_t)(hc + nt * 16 + ml) * 288 + step * 32 + qd * 8];
            bfv[nt] = *(const short8*)&Wv_i[(size_t)(hc + nt * 16 + ml) * 288 + step * 32 + qd * 8];
        }
#pragma unroll
        for (int nt = 0; nt < 2; ++nt) {
            kacc[nt] = __builtin_amdgcn_mfma_f32_16x16x32_bf16(af, bfk[nt], kacc[nt], 0, 0, 0);
            vacc[nt] = __builtin_amdgcn_mfma_f32_16x16x32_bf16(af, bfv[nt], vacc[nt], 0, 0, 0);
        }
    }

    // ---- epilogues to LDS ----
    if (wave < 8) {
#pragma unroll
        for (int nt = 0; nt < 2; ++nt) {
            const float bsq = bq[i * 256 + hc + nt * 16 + ml];
            const int r0 = wave * 16 + qd * 4;
#pragma unroll
            for (int r = 0; r < 4; ++r)
                q_s[r0 + r][nt * 16 + ml] = (short)f2bf((qacc[nt][r] + bsq) * QSC);
        }
    }
#pragma unroll
    for (int nt = 0; nt < 2; ++nt) {
        const float bsk = bk[i * 256 + hc + nt * 16 + ml];
        const float bsvv = bv[i * 256 + hc + nt * 16 + ml];
        const int s0 = wave * 16 + qd * 4;
#pragma unroll
        for (int r = 0; r < 4; ++r)
            k_s[s0 + r][nt * 16 + ml] = (short)f2bf(kacc[nt][r] + bsk);
        short4v s;
        s.x = (short)f2bf(vacc[nt][0] + bsvv);
        s.y = (short)f2bf(vacc[nt][1] + bsvv);
        s.z = (short)f2bf(vacc[nt][2] + bsvv);
        s.w = (short)f2bf(vacc[nt][3] + bsvv);
        *(short4v*)&vT_s[nt * 16 + ml][s0] = s;
    }
    __syncthreads();

    // ---- attention; waves 0..7, wave owns t rows wave*16..+16 ----
    if (wave >= 8) return;
    short* Pw = &P_s[wave][0];
    {
        const int t0 = wave * 16;
        const int tb = t0 + qd * 4;

        // mask bits hoisted above the QK chain (independent loads)
        uint4 wlo[4], whi[4];
#pragma unroll
        for (int r = 0; r < 4; ++r) {
            const unsigned int* p = mb + (bb * 128 + tb + r) * 8;
            wlo[r] = *(const uint4*)p;
            whi[r] = *(const uint4*)(p + 4);
        }

        short8 af = *(const short8*)&q_s[t0 + ml][qd * 8];

        f32x4 sacc[16];
#pragma unroll
        for (int nt = 0; nt < 16; ++nt) sacc[nt] = {0.f, 0.f, 0.f, 0.f};
#pragma unroll
        for (int nt = 0; nt < 16; ++nt) {
            short8 bf = *(const short8*)&k_s[nt * 16 + ml][qd * 8];
            sacc[nt] = __builtin_amdgcn_mfma_f32_16x16x32_bf16(af, bf, sacc[nt], 0, 0, 0);
        }

        f32x4 rs = {0.f, 0.f, 0.f, 0.f};
#pragma unroll
        for (int nt = 0; nt < 16; ++nt) {
#pragma unroll
            for (int r = 0; r < 4; ++r) {
                unsigned int w;
                switch (nt >> 1) {
                    case 0: w = wlo[r].x; break; case 1: w = wlo[r].y; break;
                    case 2: w = wlo[r].z; break; case 3: w = wlo[r].w; break;
                    case 4: w = whi[r].x; break; case 5: w = whi[r].y; break;
                    case 6: w = whi[r].z; break; default: w = whi[r].w; break;
                }
                const bool mk = (w >> ((nt & 1) * 16 + ml)) & 1u;
                float e = mk ? __builtin_amdgcn_exp2f(sacc[nt][r]) : 0.f;
                sacc[nt][r] = e;
                rs[r] += e;
            }
        }
#pragma unroll
        for (int off = 1; off <= 8; off <<= 1) {
#pragma unroll
            for (int r = 0; r < 4; ++r) rs[r] += __shfl_xor(rs[r], off);
        }
        f32x4 pinv, pfill;
#pragma unroll
        for (int r = 0; r < 4; ++r) {
            const bool z = (rs[r] == 0.f);
            pinv[r]  = z ? 0.f : 1.f / rs[r];
            pfill[r] = z ? (1.f / 256.f) : 0.f;
        }

        f32x4 oacc[2];
        oacc[0] = {0.f, 0.f, 0.f, 0.f};
        oacc[1] = {0.f, 0.f, 0.f, 0.f};
        // four s-quarters through the quartered P buffer; ks order 0..7 kept
#pragma unroll
        for (int quar = 0; quar < 4; ++quar) {
#pragma unroll
            for (int nt4 = 0; nt4 < 4; ++nt4) {
                const int nt = quar * 4 + nt4;
                const int sgrp = 2 * nt4 + (ml >> 3);
                const int pos = ml & 7;
#pragma unroll
                for (int r = 0; r < 4; ++r) {
                    const float p = sacc[nt][r] * pinv[r] + pfill[r];
                    Pw[(sgrp * 16 + qd * 4 + r) * 8 + pos] = (short)f2bf(p);
                }
            }
#pragma unroll
            for (int ksl = 0; ksl < 2; ++ksl) {
                const int ks = quar * 2 + ksl;
                short8 pa = *(const short8*)&Pw[((ksl * 4 + qd) * 16 + ml) * 8];
#pragma unroll
                for (int n2 = 0; n2 < 2; ++n2) {
                    short8 vf = *(const short8*)&vT_s[n2 * 16 + ml][ks * 32 + qd * 8];
                    oacc[n2] = __builtin_amdgcn_mfma_f32_16x16x32_bf16(pa, vf, oacc[n2], 0, 0, 0);
                }
            }
        }

#pragma unroll
        for (int n2 = 0; n2 < 2; ++n2) {
            const int d = hc + n2 * 16 + ml;
#pragma unroll
            for (int r = 0; r < 4; ++r)
                yb[(size_t)(bb * 128 + tb + r) * 256 + d] = (short)f2bf(oacc[n2][r]);
        }
    }
}

// ---------------------------------------------------------------------------
// proj2 (UNCHANGED from r11): out = sum_i O_i @ Wp_i + ax1 @ Weff + sum_i bp_i
// ---------------------------------------------------------------------------
__global__ __launch_bounds__(256) void proj2(
    const short* __restrict__ yb, const short* __restrict__ WpT,
    const short* __restrict__ ax1p, const short* __restrict__ WeffT,
    const float* __restrict__ bp, float* __restrict__ out)
{
    const int bx = blockIdx.x;
    const int m0 = (bx >> 2) * 16, n0 = (bx & 3) * 64;
    const int tid = threadIdx.x;
    const int wave = tid >> 6, lane = tid & 63;
    const int qd = lane >> 4, ml = lane & 15;
    const int col = n0 + wave * 16 + ml;

    f32x4 acc = {0.f, 0.f, 0.f, 0.f};

    for (int i = 0; i < 3; ++i) {
        const short* A = yb + (size_t)i * 1024 * 256;
        const short* W = WpT + (size_t)i * 256 * 256;
#pragma unroll
        for (int step = 0; step < 8; ++step) {
            short8 af = *(const short8*)&A[(size_t)(m0 + ml) * 256 + step * 32 + qd * 8];
            short8 bf = *(const short8*)&W[(size_t)col * 256 + step * 32 + qd * 8];
            acc = __builtin_amdgcn_mfma_f32_16x16x32_bf16(af, bf, acc, 0, 0, 0);
        }
    }
    {   // vaux term: ax1p(1024x32) @ WeffT, single K-step
        short8 af = *(const short8*)&ax1p[(size_t)(m0 + ml) * 32 + qd * 8];
        short8 bf = *(const short8*)&WeffT[(size_t)col * 32 + qd * 8];
        acc = __builtin_amdgcn_mfma_f32_16x16x32_bf16(af, bf, acc, 0, 0, 0);
    }
    const float b3 = bp[col] + bp[256 + col] + bp[512 + col];
    const int row0 = m0 + qd * 4;
#pragma unroll
    for (int r = 0; r < 4; ++r)
        out[(size_t)(row0 + r) * 256 + col] = acc[r] + b3;
}

extern "C" void kernel_launch(void* const* d_in, const int* in_sizes, int n_in,
                              void* d_out, int out_size, void* d_ws, size_t ws_size,
                              hipStream_t stream)
{
    const float* x1  = (const float*)d_in[0];
    const float* x2  = (const float*)d_in[1];
    const float* ax1 = (const float*)d_in[2];
    const float* ax2 = (const float*)d_in[3];
    const int*   mk  = (const int*)d_in[4];
    const float* Wq  = (const float*)d_in[5];
    const float* bq  = (const float*)d_in[6];
    const float* Wk  = (const float*)d_in[7];
    const float* bk  = (const float*)d_in[8];
    const float* Wv  = (const float*)d_in[9];
    const float* bv  = (const float*)d_in[10];
    const float* Wp  = (const float*)d_in[11];
    const float* bp  = (const float*)d_in[12];

    char* w = (char*)d_ws;
    short* x1b   = (short*)(w + 0);              // 512 KB
    short* A2    = (short*)(w + 524288);         // 1.125 MB
    short* ax1p  = (short*)(w + 1703936);        // 64 KB
    short* WqT   = (short*)(w + 1769472);        // 384 KB
    short* WkT   = (short*)(w + 2162688);        // 432 KB
    short* WvT   = (short*)(w + 2605056);        // 432 KB
    short* WpT   = (short*)(w + 3047424);        // 384 KB
    unsigned int* mbits = (unsigned int*)(w + 3440640);   // 96 KB
    short* WeffT = (short*)(w + 3538944);        // 16 KB
    short* yb    = (short*)(w + 3555328);        // 1.5 MB

    prep<<<dim3(956), 256, 0, stream>>>(x1, x2, ax1, ax2, mk, Wq, Wk, Wv, Wp,
                                        x1b, A2, ax1p, mbits, WqT, WkT, WvT, WpT);
    qkv_attn<<<dim3(193), 1024, 0, stream>>>(x1b, A2, WqT, WkT, WvT, Wv, WpT,
                                             bq, bk, bv, mbits, yb, WeffT);
    proj2<<<dim3(256), 256, 0, stream>>>(yb, WpT, ax1p, WeffT, bp, (float*)d_out);
}

// Round 7
// 115.792 us; speedup vs baseline: 1.1294x; 1.0036x over previous
//
#include <hip/hip_runtime.h>
#include <hip/hip_bf16.h>

// B=8, T1=128, T2=256, C=256, H=8, hd=32, E=32, A1=16, NTYPE=3. fp32 in HBM.
// Round 15: kill the WeffT straggler. Evidence: r9/r11/r14 (wildly different
// qkv interiors) all = ~116us, and r11's profile (MfmaUtil 2.3%, occ 7.3%,
// 224 GB/s, 43.8us) fits ONE block running ~40us serial while the grid
// drains: the single bx==192 WeffT block (24 serial cold-HBM step-rounds,
// 64 scattered WpT lines each). Fix: WeffT split across 16 blocks (16 n-rows
// each, wave 0, step loop unrolled -> 8-deep MLP), co-resident with the 192
// attention blocks (grid 208). Per-element (i,step) acc order and fragments
// unchanged -> bit-identical. proj2: #pragma unroll on i-loop (load MLP;
// acc chain order preserved). prep byte-identical to r14.
#define NC 256
#define HD 32

typedef __attribute__((ext_vector_type(8))) short short8;
typedef __attribute__((ext_vector_type(4))) short short4v;
typedef __attribute__((ext_vector_type(4))) float f32x4;

#define QSC (0.17677669529663687f * 1.4426950408889634f)  // 1/sqrt(32)*log2(e)

__device__ __forceinline__ unsigned short f2bf(float f) {
    union { float f; unsigned u; } v; v.f = f;
    unsigned r = v.u + 0x7fffu + ((v.u >> 16) & 1u);   // RNE
    return (unsigned short)(r >> 16);
}
__device__ __forceinline__ short8 cvt8(float4 a, float4 b) {
    short8 s;
    s[0] = (short)f2bf(a.x); s[1] = (short)f2bf(a.y);
    s[2] = (short)f2bf(a.z); s[3] = (short)f2bf(a.w);
    s[4] = (short)f2bf(b.x); s[5] = (short)f2bf(b.y);
    s[6] = (short)f2bf(b.z); s[7] = (short)f2bf(b.w);
    return s;
}

// ---------------------------------------------------------------------------
// prep (UNCHANGED from r14): activations + masks + weight transposes.
// ---------------------------------------------------------------------------
__global__ __launch_bounds__(256) void prep(
    const float* __restrict__ x1, const float* __restrict__ x2,
    const float* __restrict__ ax1, const float* __restrict__ ax2,
    const int* __restrict__ masks,
    const float* __restrict__ Wq, const float* __restrict__ Wk,
    const float* __restrict__ Wv, const float* __restrict__ Wp,
    short* __restrict__ x1b, short* __restrict__ A2, short* __restrict__ ax1p,
    unsigned int* __restrict__ mb,
    short* __restrict__ WqT, short* __restrict__ WkT, short* __restrict__ WvT,
    short* __restrict__ WpT)
{
    const int bx = blockIdx.x, tid = threadIdx.x;
    const short8 zero8 = {0, 0, 0, 0, 0, 0, 0, 0};

    if (bx < 64) {
        const size_t base = ((size_t)bx * 256 + tid) * 16;
        const float* p = x1 + base;
        float4 a = *(const float4*)p,       b = *(const float4*)(p + 4);
        float4 c = *(const float4*)(p + 8), d = *(const float4*)(p + 12);
        *(short8*)&x1b[base]     = cvt8(a, b);
        *(short8*)&x1b[base + 8] = cvt8(c, d);
    } else if (bx < 352) {
        const int g = (bx - 64) * 256 + tid;
        const int row = g / 36, c8 = g - row * 36;
        short8 s;
        if (c8 < 32) {
            const float* p = x2 + (size_t)row * 256 + c8 * 8;
            s = cvt8(*(const float4*)p, *(const float4*)(p + 4));
        } else if (c8 < 34) {
            const float* p = ax2 + (size_t)row * 16 + (c8 - 32) * 8;
            s = cvt8(*(const float4*)p, *(const float4*)(p + 4));
        } else {
            s = zero8;
        }
        *(short8*)&A2[(size_t)row * 288 + c8 * 8] = s;
    } else if (bx < 356) {
        const int row = (bx - 352) * 256 + tid;
        const float* p = ax1 + (size_t)row * 16;
        float4 a = *(const float4*)p,       b = *(const float4*)(p + 4);
        float4 c = *(const float4*)(p + 8), d = *(const float4*)(p + 12);
        short* o = ax1p + (size_t)row * 32;
        *(short8*)o        = cvt8(a, b);
        *(short8*)(o + 8)  = cvt8(c, d);
        *(short8*)(o + 16) = zero8;
        *(short8*)(o + 24) = zero8;
    } else if (bx < 548) {
        const int r0 = (bx - 356) * 16;
        const int wave = tid >> 6, lane = tid & 63;
        for (int rr = 0; rr < 16; ++rr) {
            const int row = r0 + rr;
            const int mk = masks[(size_t)row * 256 + tid];
            unsigned long long bal = __ballot(mk != 0);
            if (lane == 0) {
                mb[row * 8 + wave * 2 + 0] = (unsigned int)bal;
                mb[row * 8 + wave * 2 + 1] = (unsigned int)(bal >> 32);
            }
        }
    } else if (bx < 644) {
        const int idx = bx - 548, i = idx >> 5, k8 = idx & 31;
        const int n = tid;
        const float* W = Wq + (size_t)i * 256 * 256;
        short8 s;
#pragma unroll
        for (int j = 0; j < 8; ++j) s[j] = (short)f2bf(W[(size_t)(k8 * 8 + j) * 256 + n]);
        *(short8*)&WqT[(size_t)i * 256 * 256 + (size_t)n * 256 + k8 * 8] = s;
    } else if (bx < 860) {
        const int idx0 = bx - 644;
        const int kv = idx0 / 108, idx = idx0 % 108;
        const int i = idx / 36, k8 = idx % 36;
        const int n = tid;
        const float* W = (kv ? Wv : Wk) + (size_t)i * 288 * 256;
        short* O = (kv ? WvT : WkT) + (size_t)i * 256 * 288;
        short8 s;
#pragma unroll
        for (int j = 0; j < 8; ++j) {
            const int kp = k8 * 8 + j;
            const int src = (kp < 256) ? kp : (kp < 272 ? kp + 16 : -1);
            s[j] = (src >= 0) ? (short)f2bf(W[(size_t)src * 256 + n]) : (short)0;
        }
        *(short8*)&O[(size_t)n * 288 + k8 * 8] = s;
    } else {
        const int idx = bx - 860, i = idx >> 5, k8 = idx & 31;
        const int n = tid;
        const float* W = Wp + (size_t)i * 256 * 256;
        short8 s;
#pragma unroll
        for (int j = 0; j < 8; ++j) s[j] = (short)f2bf(W[(size_t)(k8 * 8 + j) * 256 + n]);
        *(short8*)&WpT[(size_t)i * 256 * 256 + (size_t)n * 256 + k8 * 8] = s;
    }
}

// ---------------------------------------------------------------------------
// qkv_attn: 208 blocks x 1024 threads. bx<192: (i,b,h) attention (16 waves:
// K/V s-rows 16/wave, Q+attn on waves 0-7). bx in [192,208): WeffT n-rows
// [16(bx-192), +16) on wave 0, step loop unrolled for MLP.
// ---------------------------------------------------------------------------
__global__ __launch_bounds__(1024) void qkv_attn(
    const short* __restrict__ x1b, const short* __restrict__ A2,
    const short* __restrict__ WqT, const short* __restrict__ WkT,
    const short* __restrict__ WvT, const float* __restrict__ Wv,
    const short* __restrict__ WpT,
    const float* __restrict__ bq, const float* __restrict__ bk,
    const float* __restrict__ bv, const unsigned int* __restrict__ mb,
    short* __restrict__ yb, short* __restrict__ WeffT)
{
    const int tid = threadIdx.x;
    const int wave = tid >> 6, lane = tid & 63;
    const int qd = lane >> 4, ml = lane & 15;
    const int bx = blockIdx.x;

    if (bx >= 192) {   // ---- WeffT n-rows [16*wb, +16), wave 0 only ----
        if (wave != 0) return;
        const int wb = bx - 192;
        const int n = wb * 16 + ml;
        f32x4 acc = {0.f, 0.f, 0.f, 0.f};
        for (int i = 0; i < 3; ++i) {
            const float* Wvp = Wv + (size_t)i * 288 * 256;
            const short* Wpt = WpT + (size_t)i * 256 * 256;
#pragma unroll
            for (int step = 0; step < 8; ++step) {
                const float* ap = Wvp + (size_t)(256 + ml) * 256 + step * 32 + qd * 8;
                short8 af = cvt8(*(const float4*)ap, *(const float4*)(ap + 4));
                short8 bf = *(const short8*)&Wpt[(size_t)n * 256 + step * 32 + qd * 8];
                acc = __builtin_amdgcn_mfma_f32_16x16x32_bf16(af, bf, acc, 0, 0, 0);
            }
        }
#pragma unroll
        for (int r = 0; r < 4; ++r) {
            WeffT[n * 32 + qd * 4 + r] = (short)f2bf(acc[r]);
            WeffT[n * 32 + 16 + qd * 4 + r] = 0;
        }
        return;
    }

    const int i = bx >> 6, b = (bx >> 3) & 7, h = bx & 7;
    const size_t bb = (size_t)i * 8 + b;
    const int hc = h * 32;

    __shared__ short q_s[128][40];     // 10240 B
    __shared__ short k_s[256][40];     // 20480 B
    __shared__ short vT_s[32][264];    // 16896 B
    __shared__ short P_s[8][1024];     // 16384 B (4 s-quarters per wave)

    const short* Wq_i = WqT + (size_t)i * 256 * 256;
    const short* Wk_i = WkT + (size_t)i * 256 * 288;
    const short* Wv_i = WvT + (size_t)i * 256 * 288;

    // ---- fused Q+K+V GEMMs: wave w owns K/V s-rows [16w,+16); Q on w<8 ----
    f32x4 qacc[2], kacc[2], vacc[2];
#pragma unroll
    for (int nt = 0; nt < 2; ++nt) {
        qacc[nt] = {0.f, 0.f, 0.f, 0.f};
        kacc[nt] = {0.f, 0.f, 0.f, 0.f};
        vacc[nt] = {0.f, 0.f, 0.f, 0.f};
    }

    for (int step = 0; step < 8; ++step) {
        short8 afq, bfq[2], af, bfk[2], bfv[2];
        if (wave < 8) {
            afq = *(const short8*)&x1b[(size_t)(b * 128 + wave * 16 + ml) * 256 + step * 32 + qd * 8];
#pragma unroll
            for (int nt = 0; nt < 2; ++nt)
                bfq[nt] = *(const short8*)&Wq_i[(size_t)(hc + nt * 16 + ml) * 256 + step * 32 + qd * 8];
        }
        af = *(const short8*)&A2[(size_t)(b * 256 + wave * 16 + ml) * 288 + step * 32 + qd * 8];
#pragma unroll
        for (int nt = 0; nt < 2; ++nt) {
            bfk[nt] = *(const short8*)&Wk_i[(size_t)(hc + nt * 16 + ml) * 288 + step * 32 + qd * 8];
            bfv[nt] = *(const short8*)&Wv_i[(size_t)(hc + nt * 16 + ml) * 288 + step * 32 + qd * 8];
        }
        if (wave < 8) {
#pragma unroll
            for (int nt = 0; nt < 2; ++nt)
                qacc[nt] = __builtin_amdgcn_mfma_f32_16x16x32_bf16(afq, bfq[nt], qacc[nt], 0, 0, 0);
        }
#pragma unroll
        for (int nt = 0; nt < 2; ++nt) {
            kacc[nt] = __builtin_amdgcn_mfma_f32_16x16x32_bf16(af, bfk[nt], kacc[nt], 0, 0, 0);
            vacc[nt] = __builtin_amdgcn_mfma_f32_16x16x32_bf16(af, bfv[nt], vacc[nt], 0, 0, 0);
        }
    }
    {   // peeled step 8: K/V only (A2/W cols 256..287)
        const int step = 8;
        short8 af, bfk[2], bfv[2];
        af = *(const short8*)&A2[(size_t)(b * 256 + wave * 16 + ml) * 288 + step * 32 + qd * 8];
#pragma unroll
        for (int nt = 0; nt < 2; ++nt) {
            bfk[nt] = *(const short8*)&Wk_i[(size_t)(hc + nt * 16 + ml) * 288 + step * 32 + qd * 8];
            bfv[nt] = *(const short8*)&Wv_i[(size_t)(hc + nt * 16 + ml) * 288 + step * 32 + qd * 8];
        }
#pragma unroll
        for (int nt = 0; nt < 2; ++nt) {
            kacc[nt] = __builtin_amdgcn_mfma_f32_16x16x32_bf16(af, bfk[nt], kacc[nt], 0, 0, 0);
            vacc[nt] = __builtin_amdgcn_mfma_f32_16x16x32_bf16(af, bfv[nt], vacc[nt], 0, 0, 0);
        }
    }

    // ---- epilogues to LDS ----
    if (wave < 8) {
#pragma unroll
        for (int nt = 0; nt < 2; ++nt) {
            const float bsq = bq[i * 256 + hc + nt * 16 + ml];
            const int r0 = wave * 16 + qd * 4;
#pragma unroll
            for (int r = 0; r < 4; ++r)
                q_s[r0 + r][nt * 16 + ml] = (short)f2bf((qacc[nt][r] + bsq) * QSC);
        }
    }
#pragma unroll
    for (int nt = 0; nt < 2; ++nt) {
        const float bsk = bk[i * 256 + hc + nt * 16 + ml];
        const float bsvv = bv[i * 256 + hc + nt * 16 + ml];
        const int s0 = wave * 16 + qd * 4;
#pragma unroll
        for (int r = 0; r < 4; ++r)
            k_s[s0 + r][nt * 16 + ml] = (short)f2bf(kacc[nt][r] + bsk);
        short4v s;
        s.x = (short)f2bf(vacc[nt][0] + bsvv);
        s.y = (short)f2bf(vacc[nt][1] + bsvv);
        s.z = (short)f2bf(vacc[nt][2] + bsvv);
        s.w = (short)f2bf(vacc[nt][3] + bsvv);
        *(short4v*)&vT_s[nt * 16 + ml][s0] = s;
    }
    __syncthreads();

    // ---- attention; waves 0..7, wave owns t rows wave*16..+16 ----
    if (wave >= 8) return;
    short* Pw = &P_s[wave][0];
    {
        const int t0 = wave * 16;
        const int tb = t0 + qd * 4;

        // mask bits hoisted above the QK chain (independent loads)
        uint4 wlo[4], whi[4];
#pragma unroll
        for (int r = 0; r < 4; ++r) {
            const unsigned int* p = mb + (bb * 128 + tb + r) * 8;
            wlo[r] = *(const uint4*)p;
            whi[r] = *(const uint4*)(p + 4);
        }

        short8 af = *(const short8*)&q_s[t0 + ml][qd * 8];

        f32x4 sacc[16];
#pragma unroll
        for (int nt = 0; nt < 16; ++nt) sacc[nt] = {0.f, 0.f, 0.f, 0.f};
#pragma unroll
        for (int nt = 0; nt < 16; ++nt) {
            short8 bf = *(const short8*)&k_s[nt * 16 + ml][qd * 8];
            sacc[nt] = __builtin_amdgcn_mfma_f32_16x16x32_bf16(af, bf, sacc[nt], 0, 0, 0);
        }

        f32x4 rs = {0.f, 0.f, 0.f, 0.f};
#pragma unroll
        for (int nt = 0; nt < 16; ++nt) {
#pragma unroll
            for (int r = 0; r < 4; ++r) {
                unsigned int w;
                switch (nt >> 1) {
                    case 0: w = wlo[r].x; break; case 1: w = wlo[r].y; break;
                    case 2: w = wlo[r].z; break; case 3: w = wlo[r].w; break;
                    case 4: w = whi[r].x; break; case 5: w = whi[r].y; break;
                    case 6: w = whi[r].z; break; default: w = whi[r].w; break;
                }
                const bool mk = (w >> ((nt & 1) * 16 + ml)) & 1u;
                float e = mk ? __builtin_amdgcn_exp2f(sacc[nt][r]) : 0.f;
                sacc[nt][r] = e;
                rs[r] += e;
            }
        }
#pragma unroll
        for (int off = 1; off <= 8; off <<= 1) {
#pragma unroll
            for (int r = 0; r < 4; ++r) rs[r] += __shfl_xor(rs[r], off);
        }
        f32x4 pinv, pfill;
#pragma unroll
        for (int r = 0; r < 4; ++r) {
            const bool z = (rs[r] == 0.f);
            pinv[r]  = z ? 0.f : 1.f / rs[r];
            pfill[r] = z ? (1.f / 256.f) : 0.f;
        }

        f32x4 oacc[2];
        oacc[0] = {0.f, 0.f, 0.f, 0.f};
        oacc[1] = {0.f, 0.f, 0.f, 0.f};
        // four s-quarters through the quartered P buffer; ks order 0..7 kept
#pragma unroll
        for (int quar = 0; quar < 4; ++quar) {
#pragma unroll
            for (int nt4 = 0; nt4 < 4; ++nt4) {
                const int nt = quar * 4 + nt4;
                const int sgrp = 2 * nt4 + (ml >> 3);
                const int pos = ml & 7;
#pragma unroll
                for (int r = 0; r < 4; ++r) {
                    const float p = sacc[nt][r] * pinv[r] + pfill[r];
                    Pw[(sgrp * 16 + qd * 4 + r) * 8 + pos] = (short)f2bf(p);
                }
            }
#pragma unroll
            for (int ksl = 0; ksl < 2; ++ksl) {
                const int ks = quar * 2 + ksl;
                short8 pa = *(const short8*)&Pw[((ksl * 4 + qd) * 16 + ml) * 8];
#pragma unroll
                for (int n2 = 0; n2 < 2; ++n2) {
                    short8 vf = *(const short8*)&vT_s[n2 * 16 + ml][ks * 32 + qd * 8];
                    oacc[n2] = __builtin_amdgcn_mfma_f32_16x16x32_bf16(pa, vf, oacc[n2], 0, 0, 0);
                }
            }
        }

#pragma unroll
        for (int n2 = 0; n2 < 2; ++n2) {
            const int d = hc + n2 * 16 + ml;
#pragma unroll
            for (int r = 0; r < 4; ++r)
                yb[(size_t)(bb * 128 + tb + r) * 256 + d] = (short)f2bf(oacc[n2][r]);
        }
    }
}

// ---------------------------------------------------------------------------
// proj2: out = sum_i O_i @ Wp_i + ax1 @ Weff + sum_i bp_i. i-loop unrolled
// for load MLP (acc chain order unchanged -> bit-identical).
// ---------------------------------------------------------------------------
__global__ __launch_bounds__(256) void proj2(
    const short* __restrict__ yb, const short* __restrict__ WpT,
    const short* __restrict__ ax1p, const short* __restrict__ WeffT,
    const float* __restrict__ bp, float* __restrict__ out)
{
    const int bx = blockIdx.x;
    const int m0 = (bx >> 2) * 16, n0 = (bx & 3) * 64;
    const int tid = threadIdx.x;
    const int wave = tid >> 6, lane = tid & 63;
    const int qd = lane >> 4, ml = lane & 15;
    const int col = n0 + wave * 16 + ml;

    f32x4 acc = {0.f, 0.f, 0.f, 0.f};

#pragma unroll
    for (int i = 0; i < 3; ++i) {
        const short* A = yb + (size_t)i * 1024 * 256;
        const short* W = WpT + (size_t)i * 256 * 256;
#pragma unroll
        for (int step = 0; step < 8; ++step) {
            short8 af = *(const short8*)&A[(size_t)(m0 + ml) * 256 + step * 32 + qd * 8];
            short8 bf = *(const short8*)&W[(size_t)col * 256 + step * 32 + qd * 8];
            acc = __builtin_amdgcn_mfma_f32_16x16x32_bf16(af, bf, acc, 0, 0, 0);
        }
    }
    {   // vaux term: ax1p(1024x32) @ WeffT, single K-step
        short8 af = *(const short8*)&ax1p[(size_t)(m0 + ml) * 32 + qd * 8];
        short8 bf = *(const short8*)&WeffT[(size_t)col * 32 + qd * 8];
        acc = __builtin_amdgcn_mfma_f32_16x16x32_bf16(af, bf, acc, 0, 0, 0);
    }
    const float b3 = bp[col] + bp[256 + col] + bp[512 + col];
    const int row0 = m0 + qd * 4;
#pragma unroll
    for (int r = 0; r < 4; ++r)
        out[(size_t)(row0 + r) * 256 + col] = acc[r] + b3;
}

extern "C" void kernel_launch(void* const* d_in, const int* in_sizes, int n_in,
                              void* d_out, int out_size, void* d_ws, size_t ws_size,
                              hipStream_t stream)
{
    const float* x1  = (const float*)d_in[0];
    const float* x2  = (const float*)d_in[1];
    const float* ax1 = (const float*)d_in[2];
    const float* ax2 = (const float*)d_in[3];
    const int*   mk  = (const int*)d_in[4];
    const float* Wq  = (const float*)d_in[5];
    const float* bq  = (const float*)d_in[6];
    const float* Wk  = (const float*)d_in[7];
    const float* bk  = (const float*)d_in[8];
    const float* Wv  = (const float*)d_in[9];
    const float* bv  = (const float*)d_in[10];
    const float* Wp  = (const float*)d_in[11];
    const float* bp  = (const float*)d_in[12];

    char* w = (char*)d_ws;
    short* x1b   = (short*)(w + 0);              // 512 KB
    short* A2    = (short*)(w + 524288);         // 1.125 MB
    short* ax1p  = (short*)(w + 1703936);        // 64 KB
    short* WqT   = (short*)(w + 1769472);        // 384 KB
    short* WkT   = (short*)(w + 2162688);        // 432 KB
    short* WvT   = (short*)(w + 2605056);        // 432 KB
    short* WpT   = (short*)(w + 3047424);        // 384 KB
    unsigned int* mbits = (unsigned int*)(w + 3440640);   // 96 KB
    short* WeffT = (short*)(w + 3538944);        // 16 KB
    short* yb    = (short*)(w + 3555328);        // 1.5 MB

    prep<<<dim3(956), 256, 0, stream>>>(x1, x2, ax1, ax2, mk, Wq, Wk, Wv, Wp,
                                        x1b, A2, ax1p, mbits, WqT, WkT, WvT, WpT);
    qkv_attn<<<dim3(208), 1024, 0, stream>>>(x1b, A2, WqT, WkT, WvT, Wv, WpT,
                                             bq, bk, bv, mbits, yb, WeffT);
    proj2<<<dim3(256), 256, 0, stream>>>(yb, WpT, ax1p, WeffT, bp, (float*)d_out);
}